// Round 1
// baseline (20215.739 us; speedup 1.0000x reference)
//
#include <hip/hip_runtime.h>
#include <hip/hip_bf16.h>

// TGCN: B=64, T=500, N=21, HID=128.
// Round 8: column-split wave decomposition for weight dedup.
//   Lane = (pair-slot p = lane&7) x (row-group rg = lane>>3).
//   Each lane owns 2 column-pairs: f0A = gw*16+p (+64), f0B = f0A+8 (+64),
//   and 3 rows: rg*3 + r (rows 21..23 are zero padding; rg==7 is all-pad).
//   -> each weight float4 is loaded by exactly ONE lane-group per tick:
//      per-CU weight traffic 2.3MB -> 576KB per tick (the round-7 wall).
//   -> one broadcast H ds_read_b128 feeds BOTH pairs: LDS b128 count /2.
//   Cost: intermediates lose wave-locality -> 2 block barriers per tick:
//      alpha: A:P1(k+1) || B:P5(k-1),P3(k)   [b1]
//      beta : A:P2(k+1)+sax || B:P4(k)       [b2]
//   All H/intermediate arrays padded to stride S=132 floats so the 8
//   distinct row addresses of a broadcast b128 cover all 32 banks once.
//   NEVER reorder per-element sums in the recurrence: every (row,f)
//   accumulation chain is bit-identical to round 7 (same c/k order,
//   same a-chunk-then-q-chunk order); only lane assignment changed.
//   Output reduction is fp64 (reassociation there is safe).

#define NN 21
#define NROW 24            // padded rows (21,22,23 zero)
#define S 132              // padded float stride for H arrays (132%32==4)
#define SV4 33             // float4 stride
#define HID 128
#define TSTEPS 500
#define EDGES 210
#define NTHREADS 512       // 8 waves: 4 per group
#define RPT 3              // rows per row-group

// ws layout (float offsets) — unchanged from round 7
#define WS_A     0        // NROW*NN floats (pad rows zeroed on build)
#define WS_VEC   1600     // 9*128
#define WS_LZR1  3200     // 32*256*4 floats4 -> 32768 floats
#define WS_LH1   36000    // 32*128*4
#define WS_WE2   52400    // 32*384*4
#define WS_LZR2  101600   // 32*256*4
#define WS_LH2   134400   // 32*128*4

typedef float v2f __attribute__((ext_vector_type(2)));

__device__ __forceinline__ v2f lo2(float4 w) { v2f v = {w.x, w.y}; return v; }
__device__ __forceinline__ v2f hi2(float4 w) { v2f v = {w.z, w.w}; return v; }
// acc.{x,y} += s * w.{x,y}  -> v_pk_fma_f32
__device__ __forceinline__ void pkf(v2f& acc, float s, v2f w) {
    v2f ss = {s, s};
    acc = __builtin_elementwise_fma(ss, w, acc);
}
__device__ __forceinline__ float sigmoidf(float v) {
    return 1.0f / (1.0f + expf(-v));
}

// ---- Prologue: build normalized adjacency A (21x21) in fp64, store fp32 ----
__global__ void build_A(const int* __restrict__ ei, const float* __restrict__ ew,
                        float* __restrict__ Aout) {
    __shared__ double deg[NN];
    __shared__ double dinv[NN];
    __shared__ double Asm[NN * NN];
    int t = threadIdx.x;
    for (int k = t; k < NN * NN; k += blockDim.x) Asm[k] = 0.0;
    if (t < NN) deg[t] = 1.0;  // self loop weight 1
    __syncthreads();
    if (t == 0) {
        for (int e = 0; e < EDGES; e++) deg[ei[EDGES + e]] += (double)ew[e];
        for (int i = 0; i < NN; i++) dinv[i] = deg[i] > 0.0 ? 1.0 / sqrt(deg[i]) : 0.0;
        for (int e = 0; e < EDGES; e++) {
            int s = ei[e], d = ei[EDGES + e];
            Asm[d * NN + s] += dinv[s] * (double)ew[e] * dinv[d];
        }
        for (int i = 0; i < NN; i++) Asm[i * NN + i] += dinv[i] * dinv[i];
    }
    __syncthreads();
    for (int k = t; k < NROW * NN; k += blockDim.x)
        Aout[k] = (k < NN * NN) ? (float)Asm[k] : 0.0f;
}

// ---- Prologue: repack bottom halves of (256,128) concat weights ----------
// Pair-interleaved layout: float4 idx (c, gate, k2, f0) =
//   c*(ngate*128) + gate*128 + k2*64 + f0,  k = 4c + 2*k2
// contents {w[k][f0], w[k][f0+64], w[k+1][f0], w[k+1][f0+64]}
__global__ void pack_bot(const float* __restrict__ w0, const float* __restrict__ w1,
                         float4* __restrict__ out, int ngate) {
    int t = blockIdx.x * blockDim.x + threadIdx.x;
    int per_c = ngate * 128;
    int total = 32 * per_c;
    if (t >= total) return;
    int c = t / per_c, rem = t - c * per_c;
    int gate = rem >> 7;
    int r2 = rem & 127;
    int k2 = r2 >> 6;
    int f0 = r2 & 63;
    int k = 4 * c + 2 * k2;
    const float* src = (gate == 0) ? w0 : w1;
    float4 v;
    v.x = src[(128 + k) * 128 + f0];
    v.y = src[(128 + k) * 128 + f0 + 64];
    v.z = src[(128 + k + 1) * 128 + f0];
    v.w = src[(128 + k + 1) * 128 + f0 + 64];
    out[t] = v;
}

// ---- Prologue: Weff2_g = Wg_2 @ lgw_2_top, pair-interleaved, fp64 accum ----
__global__ void make_weff2(const float* __restrict__ Wz2, const float* __restrict__ Wr2,
                           const float* __restrict__ Wh2,
                           const float* __restrict__ lzw2, const float* __restrict__ lrw2,
                           const float* __restrict__ lhw2,
                           float4* __restrict__ out) {
    int t = blockIdx.x * blockDim.x + threadIdx.x;  // [0, 32*384)
    if (t >= 32 * 384) return;
    int c = t / 384, rem = t - c * 384;
    int g = rem >> 7;
    int r2 = rem & 127;
    int k2 = r2 >> 6;
    int f0 = r2 & 63;
    int k = 4 * c + 2 * k2;
    const float* W = (g == 0) ? Wz2 : (g == 1) ? Wr2 : Wh2;
    const float* L = (g == 0) ? lzw2 : (g == 1) ? lrw2 : lhw2;
    double a0 = 0, a1 = 0, a2 = 0, a3 = 0;
    for (int m = 0; m < 128; m++) {
        double w0 = (double)W[k * 128 + m];
        double w1 = (double)W[(k + 1) * 128 + m];
        a0 += w0 * (double)L[m * 128 + f0];
        a1 += w0 * (double)L[m * 128 + f0 + 64];
        a2 += w1 * (double)L[m * 128 + f0];
        a3 += w1 * (double)L[m * 128 + f0 + 64];
    }
    out[t] = make_float4((float)a0, (float)a1, (float)a2, (float)a3);
}

// ---- Prologue: layer-1 effective row vectors + all bias consts (fp64) ----
__global__ void make_vecs(const float* __restrict__ Wz1, const float* __restrict__ Wr1,
                          const float* __restrict__ Wh1,
                          const float* __restrict__ bz1, const float* __restrict__ br1,
                          const float* __restrict__ bh1,
                          const float* __restrict__ lzw1, const float* __restrict__ lrw1,
                          const float* __restrict__ lhw1,
                          const float* __restrict__ lzb1, const float* __restrict__ lrb1,
                          const float* __restrict__ lhb1,
                          const float* __restrict__ bz2, const float* __restrict__ br2,
                          const float* __restrict__ bh2,
                          const float* __restrict__ lzw2, const float* __restrict__ lrw2,
                          const float* __restrict__ lhw2,
                          const float* __restrict__ lzb2, const float* __restrict__ lrb2,
                          const float* __restrict__ lhb2,
                          float* __restrict__ out) {
    int t = blockIdx.x * blockDim.x + threadIdx.x;
    if (t >= 9 * 128) return;
    int v = t >> 7, f = t & 127;
    double acc = 0.0;
    if (v < 3) {
        const float* W = (v == 0) ? Wz1 : (v == 1) ? Wr1 : Wh1;   // (1,128)
        const float* L = (v == 0) ? lzw1 : (v == 1) ? lrw1 : lhw1;
        for (int m = 0; m < 128; m++) acc += (double)W[m] * (double)L[m * 128 + f];
    } else if (v < 6) {
        int g = v - 3;
        const float* bb = (g == 0) ? bz1 : (g == 1) ? br1 : bh1;
        const float* L  = (g == 0) ? lzw1 : (g == 1) ? lrw1 : lhw1;
        const float* lb = (g == 0) ? lzb1 : (g == 1) ? lrb1 : lhb1;
        for (int m = 0; m < 128; m++) acc += (double)bb[m] * (double)L[m * 128 + f];
        acc += (double)lb[f];
    } else {
        int g = v - 6;
        const float* bb = (g == 0) ? bz2 : (g == 1) ? br2 : bh2;
        const float* L  = (g == 0) ? lzw2 : (g == 1) ? lrw2 : lhw2;
        const float* lb = (g == 0) ? lzb2 : (g == 1) ? lrb2 : lhb2;
        for (int m = 0; m < 128; m++) acc += (double)bb[m] * (double)L[m * 128 + f];
        acc += (double)lb[f];
    }
    out[t] = (float)acc;
}

// ---- Main: one block per batch, layer-pipelined groups, 2 barriers/tick ----
__global__ __launch_bounds__(NTHREADS, 2) void tgcn_main(
    const float* __restrict__ x,       // (64,500,21)
    const float* __restrict__ ws,
    const float* __restrict__ cls_w,   // (128,1)
    const float* __restrict__ cls_b,   // (1,)
    float* __restrict__ out)           // (64,)
{
    const int b  = blockIdx.x;
    const int t  = threadIdx.x;
    const bool isA = (t < 256);                              // wave-uniform
    const int lt = t & 255;
    const int gw = __builtin_amdgcn_readfirstlane(lt >> 6);  // wave in group 0..3
    const int lane = t & 63;
    const int p  = lane & 7;          // pair slot
    const int rg = lane >> 3;         // row group 0..7
    const int rb = rg * RPT;          // first row of this lane
    const int f0A = gw * 16 + p;      // first pair:  cols (f0A, f0A+64)
    const int f0B = f0A + 8;          // second pair: cols (f0B, f0B+64)

    __shared__ __align__(16) float sH1[2][NROW * S];  // double-buffered
    __shared__ __align__(16) float sH2[NROW * S];
    __shared__ __align__(16) float sHR1[NROW * S];
    __shared__ __align__(16) float sHR2[NROW * S];
    __shared__ __align__(16) float sAH[NROW * S];
    __shared__ float sA[NROW * NN];
    __shared__ float sax[2][NROW];
    __shared__ double sredD[HID];
    __shared__ double sredE[HID];

    const float*  vecs = ws + WS_VEC;
    const float4* Lzr1 = (const float4*)(ws + WS_LZR1);
    const float4* Lh1  = (const float4*)(ws + WS_LH1);
    const float4* We2  = (const float4*)(ws + WS_WE2);
    const float4* Lzr2 = (const float4*)(ws + WS_LZR2);
    const float4* Lh2  = (const float4*)(ws + WS_LH2);

    const float4* HR1v = (const float4*)sHR1;
    const float4* HR2v = (const float4*)sHR2;
    const float4* AHv  = (const float4*)sAH;
    const float4* H2v  = (const float4*)sH2;

    for (int k = t; k < 2 * NROW * S; k += NTHREADS) ((float*)sH1)[k] = 0.0f;
    for (int k = t; k < NROW * S; k += NTHREADS) {
        sH2[k] = 0.0f; sHR1[k] = 0.0f; sHR2[k] = 0.0f; sAH[k] = 0.0f;
    }
    for (int k = t; k < NROW * NN; k += NTHREADS) sA[k] = ws[WS_A + k];

    // per-pair constants (two pairs per lane)
    const v2f wz1vA = {vecs[f0A],        vecs[f0A + 64]};
    const v2f wz1vB = {vecs[f0B],        vecs[f0B + 64]};
    const v2f wr1vA = {vecs[128 + f0A],  vecs[128 + f0A + 64]};
    const v2f wr1vB = {vecs[128 + f0B],  vecs[128 + f0B + 64]};
    const v2f wh1vA = {vecs[256 + f0A],  vecs[256 + f0A + 64]};
    const v2f wh1vB = {vecs[256 + f0B],  vecs[256 + f0B + 64]};
    const v2f cz1vA = {vecs[384 + f0A],  vecs[384 + f0A + 64]};
    const v2f cz1vB = {vecs[384 + f0B],  vecs[384 + f0B + 64]};
    const v2f cr1vA = {vecs[512 + f0A],  vecs[512 + f0A + 64]};
    const v2f cr1vB = {vecs[512 + f0B],  vecs[512 + f0B + 64]};
    const v2f ch1vA = {vecs[640 + f0A],  vecs[640 + f0A + 64]};
    const v2f ch1vB = {vecs[640 + f0B],  vecs[640 + f0B + 64]};
    const v2f cz2vA = {vecs[768 + f0A],  vecs[768 + f0A + 64]};
    const v2f cz2vB = {vecs[768 + f0B],  vecs[768 + f0B + 64]};
    const v2f cr2vA = {vecs[896 + f0A],  vecs[896 + f0A + 64]};
    const v2f cr2vB = {vecs[896 + f0B],  vecs[896 + f0B + 64]};
    const v2f ch2vA = {vecs[1024 + f0A], vecs[1024 + f0A + 64]};
    const v2f ch2vB = {vecs[1024 + f0B], vecs[1024 + f0B + 64]};

    __syncthreads();

    const float* xb = x + (size_t)b * (TSTEPS * NN);
    if (t < NROW) {  // sax for steps 0 and 1 (slot = s&1)
        float a0s = 0.0f, a1s = 0.0f;
        for (int j = 0; j < NN; j++) {
            a0s = fmaf(sA[t * NN + j], xb[j], a0s);
            a1s = fmaf(sA[t * NN + j], xb[NN + j], a1s);
        }
        sax[0][t] = a0s;
        sax[1][t] = a1s;
    }
    __syncthreads();

    // ---- persistent per-thread state carried across barriers ----
    float axp[RPT];                         // A: P1 -> P2
    v2f zg[RPT][2], h1c[RPT][2];            // A: P1 -> P2
    v2f ph[RPT][2], z2[RPT][2], h2c[RPT][2];// B: P4 -> P5 (crosses b2)
    double oA0 = 0.0, oA1 = 0.0, oB0 = 0.0, oB1 = 0.0;  // B output accum

    // ================= phase lambdas =================
    // P1 (A): layer-1 z,r gates for step s; reads H1 state s-1 = buf[(s+1)&1]
    auto l1_p1 = [&](int s) {
        const float* H1rd = sH1[(s + 1) & 1];
        const float4* H1c = (const float4*)H1rd;
        #pragma unroll
        for (int r = 0; r < RPT; r++) axp[r] = sax[s & 1][rb + r];
        v2f az[RPT][2], ar[RPT][2];
        #pragma unroll
        for (int r = 0; r < RPT; r++) {
            az[r][0] = __builtin_elementwise_fma((v2f){axp[r], axp[r]}, wz1vA, cz1vA);
            az[r][1] = __builtin_elementwise_fma((v2f){axp[r], axp[r]}, wz1vB, cz1vB);
            ar[r][0] = __builtin_elementwise_fma((v2f){axp[r], axp[r]}, wr1vA, cr1vA);
            ar[r][1] = __builtin_elementwise_fma((v2f){axp[r], axp[r]}, wr1vB, cr1vB);
        }
        #pragma unroll 2
        for (int c = 0; c < 32; ++c) {
            const float4 wz0A = Lzr1[c * 256 + f0A];
            const float4 wz1A = Lzr1[c * 256 + 64 + f0A];
            const float4 wr0A = Lzr1[c * 256 + 128 + f0A];
            const float4 wr1A = Lzr1[c * 256 + 192 + f0A];
            const float4 wz0B = Lzr1[c * 256 + f0B];
            const float4 wz1B = Lzr1[c * 256 + 64 + f0B];
            const float4 wr0B = Lzr1[c * 256 + 128 + f0B];
            const float4 wr1B = Lzr1[c * 256 + 192 + f0B];
            #pragma unroll
            for (int r = 0; r < RPT; r++) {
                const float4 h = H1c[(rb + r) * SV4 + c];
                pkf(az[r][0], h.x, lo2(wz0A)); pkf(az[r][0], h.y, hi2(wz0A));
                pkf(az[r][0], h.z, lo2(wz1A)); pkf(az[r][0], h.w, hi2(wz1A));
                pkf(ar[r][0], h.x, lo2(wr0A)); pkf(ar[r][0], h.y, hi2(wr0A));
                pkf(ar[r][0], h.z, lo2(wr1A)); pkf(ar[r][0], h.w, hi2(wr1A));
                pkf(az[r][1], h.x, lo2(wz0B)); pkf(az[r][1], h.y, hi2(wz0B));
                pkf(az[r][1], h.z, lo2(wz1B)); pkf(az[r][1], h.w, hi2(wz1B));
                pkf(ar[r][1], h.x, lo2(wr0B)); pkf(ar[r][1], h.y, hi2(wr0B));
                pkf(ar[r][1], h.z, lo2(wr1B)); pkf(ar[r][1], h.w, hi2(wr1B));
            }
        }
        #pragma unroll
        for (int r = 0; r < RPT; r++) {
            const int row = rb + r;
            zg[r][0].x = sigmoidf(az[r][0].x);
            zg[r][0].y = sigmoidf(az[r][0].y);
            zg[r][1].x = sigmoidf(az[r][1].x);
            zg[r][1].y = sigmoidf(az[r][1].y);
            const float rA0 = sigmoidf(ar[r][0].x);
            const float rA1 = sigmoidf(ar[r][0].y);
            const float rB0 = sigmoidf(ar[r][1].x);
            const float rB1 = sigmoidf(ar[r][1].y);
            h1c[r][0].x = H1rd[row * S + f0A];
            h1c[r][0].y = H1rd[row * S + f0A + 64];
            h1c[r][1].x = H1rd[row * S + f0B];
            h1c[r][1].y = H1rd[row * S + f0B + 64];
            sHR1[row * S + f0A]      = h1c[r][0].x * rA0;
            sHR1[row * S + f0A + 64] = h1c[r][0].y * rA1;
            sHR1[row * S + f0B]      = h1c[r][1].x * rB0;
            sHR1[row * S + f0B + 64] = h1c[r][1].y * rB1;
        }
    };

    // P2 (A): layer-1 h gate + H1 update for step s; writes buf[s&1]
    auto l1_p2 = [&](int s) {
        float* H1wr = sH1[s & 1];
        v2f ah[RPT][2];
        #pragma unroll
        for (int r = 0; r < RPT; r++) {
            ah[r][0] = __builtin_elementwise_fma((v2f){axp[r], axp[r]}, wh1vA, ch1vA);
            ah[r][1] = __builtin_elementwise_fma((v2f){axp[r], axp[r]}, wh1vB, ch1vB);
        }
        #pragma unroll 2
        for (int c = 0; c < 32; ++c) {
            const float4 wh0A = Lh1[c * 128 + f0A];
            const float4 wh1A = Lh1[c * 128 + 64 + f0A];
            const float4 wh0B = Lh1[c * 128 + f0B];
            const float4 wh1B = Lh1[c * 128 + 64 + f0B];
            #pragma unroll
            for (int r = 0; r < RPT; r++) {
                const float4 q = HR1v[(rb + r) * SV4 + c];
                pkf(ah[r][0], q.x, lo2(wh0A)); pkf(ah[r][0], q.y, hi2(wh0A));
                pkf(ah[r][0], q.z, lo2(wh1A)); pkf(ah[r][0], q.w, hi2(wh1A));
                pkf(ah[r][1], q.x, lo2(wh0B)); pkf(ah[r][1], q.y, hi2(wh0B));
                pkf(ah[r][1], q.z, lo2(wh1B)); pkf(ah[r][1], q.w, hi2(wh1B));
            }
        }
        #pragma unroll
        for (int r = 0; r < RPT; r++) {
            const int row = rb + r;
            const float n0 = fmaf(zg[r][0].x, h1c[r][0].x, (1.0f - zg[r][0].x) * tanhf(ah[r][0].x));
            const float n1 = fmaf(zg[r][0].y, h1c[r][0].y, (1.0f - zg[r][0].y) * tanhf(ah[r][0].y));
            const float n2 = fmaf(zg[r][1].x, h1c[r][1].x, (1.0f - zg[r][1].x) * tanhf(ah[r][1].x));
            const float n3 = fmaf(zg[r][1].y, h1c[r][1].y, (1.0f - zg[r][1].y) * tanhf(ah[r][1].y));
            H1wr[row * S + f0A]      = n0;
            H1wr[row * S + f0A + 64] = n1;
            H1wr[row * S + f0B]      = n2;
            H1wr[row * S + f0B + 64] = n3;
        }
    };

    // P3 (B): AH = A @ H1(state tt) for own rows/cols
    auto l2_p3 = [&](int tt) {
        const float* H1rd = sH1[tt & 1];
        v2f aa[RPT][2];
        #pragma unroll
        for (int r = 0; r < RPT; r++) { aa[r][0] = (v2f){0.0f, 0.0f}; aa[r][1] = (v2f){0.0f, 0.0f}; }
        #pragma unroll 3
        for (int j = 0; j < NN; j++) {
            const v2f hjA = {H1rd[j * S + f0A], H1rd[j * S + f0A + 64]};
            const v2f hjB = {H1rd[j * S + f0B], H1rd[j * S + f0B + 64]};
            #pragma unroll
            for (int r = 0; r < RPT; r++) {
                const float arj = sA[(rb + r) * NN + j];
                aa[r][0] = __builtin_elementwise_fma((v2f){arj, arj}, hjA, aa[r][0]);
                aa[r][1] = __builtin_elementwise_fma((v2f){arj, arj}, hjB, aa[r][1]);
            }
        }
        #pragma unroll
        for (int r = 0; r < RPT; r++) {
            const int row = rb + r;
            sAH[row * S + f0A]      = aa[r][0].x;
            sAH[row * S + f0A + 64] = aa[r][0].y;
            sAH[row * S + f0B]      = aa[r][1].x;
            sAH[row * S + f0B + 64] = aa[r][1].y;
        }
    };

    // P4 (B): layer-2 gcn + z,r gates; h-gate a-chunk partials into ph
    auto l2_p4 = [&]() {
        v2f pz[RPT][2], pr[RPT][2];
        #pragma unroll
        for (int r = 0; r < RPT; r++) {
            pz[r][0] = cz2vA; pz[r][1] = cz2vB;
            pr[r][0] = cr2vA; pr[r][1] = cr2vB;
            ph[r][0] = ch2vA; ph[r][1] = ch2vB;
        }
        for (int c = 0; c < 32; ++c) {
            float4 av[RPT], qv[RPT];
            #pragma unroll
            for (int r = 0; r < RPT; r++) {
                av[r] = AHv[(rb + r) * SV4 + c];
                qv[r] = H2v[(rb + r) * SV4 + c];
            }
            {   // pair A half
                const float4 wz0 = We2[c * 384 + f0A];
                const float4 wz1 = We2[c * 384 + 64 + f0A];
                const float4 wr0 = We2[c * 384 + 128 + f0A];
                const float4 wr1 = We2[c * 384 + 192 + f0A];
                const float4 wh0 = We2[c * 384 + 256 + f0A];
                const float4 wh1 = We2[c * 384 + 320 + f0A];
                const float4 lz0 = Lzr2[c * 256 + f0A];
                const float4 lz1 = Lzr2[c * 256 + 64 + f0A];
                const float4 lr0 = Lzr2[c * 256 + 128 + f0A];
                const float4 lr1 = Lzr2[c * 256 + 192 + f0A];
                #pragma unroll
                for (int r = 0; r < RPT; r++) {
                    const float4 a = av[r], q = qv[r];
                    pkf(pz[r][0], a.x, lo2(wz0)); pkf(pz[r][0], a.y, hi2(wz0));
                    pkf(pz[r][0], a.z, lo2(wz1)); pkf(pz[r][0], a.w, hi2(wz1));
                    pkf(pz[r][0], q.x, lo2(lz0)); pkf(pz[r][0], q.y, hi2(lz0));
                    pkf(pz[r][0], q.z, lo2(lz1)); pkf(pz[r][0], q.w, hi2(lz1));
                    pkf(pr[r][0], a.x, lo2(wr0)); pkf(pr[r][0], a.y, hi2(wr0));
                    pkf(pr[r][0], a.z, lo2(wr1)); pkf(pr[r][0], a.w, hi2(wr1));
                    pkf(pr[r][0], q.x, lo2(lr0)); pkf(pr[r][0], q.y, hi2(lr0));
                    pkf(pr[r][0], q.z, lo2(lr1)); pkf(pr[r][0], q.w, hi2(lr1));
                    pkf(ph[r][0], a.x, lo2(wh0)); pkf(ph[r][0], a.y, hi2(wh0));
                    pkf(ph[r][0], a.z, lo2(wh1)); pkf(ph[r][0], a.w, hi2(wh1));
                }
            }
            {   // pair B half
                const float4 wz0 = We2[c * 384 + f0B];
                const float4 wz1 = We2[c * 384 + 64 + f0B];
                const float4 wr0 = We2[c * 384 + 128 + f0B];
                const float4 wr1 = We2[c * 384 + 192 + f0B];
                const float4 wh0 = We2[c * 384 + 256 + f0B];
                const float4 wh1 = We2[c * 384 + 320 + f0B];
                const float4 lz0 = Lzr2[c * 256 + f0B];
                const float4 lz1 = Lzr2[c * 256 + 64 + f0B];
                const float4 lr0 = Lzr2[c * 256 + 128 + f0B];
                const float4 lr1 = Lzr2[c * 256 + 192 + f0B];
                #pragma unroll
                for (int r = 0; r < RPT; r++) {
                    const float4 a = av[r], q = qv[r];
                    pkf(pz[r][1], a.x, lo2(wz0)); pkf(pz[r][1], a.y, hi2(wz0));
                    pkf(pz[r][1], a.z, lo2(wz1)); pkf(pz[r][1], a.w, hi2(wz1));
                    pkf(pz[r][1], q.x, lo2(lz0)); pkf(pz[r][1], q.y, hi2(lz0));
                    pkf(pz[r][1], q.z, lo2(lz1)); pkf(pz[r][1], q.w, hi2(lz1));
                    pkf(pr[r][1], a.x, lo2(wr0)); pkf(pr[r][1], a.y, hi2(wr0));
                    pkf(pr[r][1], a.z, lo2(wr1)); pkf(pr[r][1], a.w, hi2(wr1));
                    pkf(pr[r][1], q.x, lo2(lr0)); pkf(pr[r][1], q.y, hi2(lr0));
                    pkf(pr[r][1], q.z, lo2(lr1)); pkf(pr[r][1], q.w, hi2(lr1));
                    pkf(ph[r][1], a.x, lo2(wh0)); pkf(ph[r][1], a.y, hi2(wh0));
                    pkf(ph[r][1], a.z, lo2(wh1)); pkf(ph[r][1], a.w, hi2(wh1));
                }
            }
        }
        #pragma unroll
        for (int r = 0; r < RPT; r++) {
            const int row = rb + r;
            z2[r][0].x = sigmoidf(pz[r][0].x);
            z2[r][0].y = sigmoidf(pz[r][0].y);
            z2[r][1].x = sigmoidf(pz[r][1].x);
            z2[r][1].y = sigmoidf(pz[r][1].y);
            const float rA0 = sigmoidf(pr[r][0].x);
            const float rA1 = sigmoidf(pr[r][0].y);
            const float rB0 = sigmoidf(pr[r][1].x);
            const float rB1 = sigmoidf(pr[r][1].y);
            h2c[r][0].x = sH2[row * S + f0A];
            h2c[r][0].y = sH2[row * S + f0A + 64];
            h2c[r][1].x = sH2[row * S + f0B];
            h2c[r][1].y = sH2[row * S + f0B + 64];
            sHR2[row * S + f0A]      = h2c[r][0].x * rA0;
            sHR2[row * S + f0A + 64] = h2c[r][0].y * rA1;
            sHR2[row * S + f0B]      = h2c[r][1].x * rB0;
            sHR2[row * S + f0B + 64] = h2c[r][1].y * rB1;
        }
    };

    // P5 (B): layer-2 h gate finish + H2 update + output accum
    auto l2_p5 = [&]() {
        #pragma unroll 2
        for (int c = 0; c < 32; ++c) {
            const float4 lh0A = Lh2[c * 128 + f0A];
            const float4 lh1A = Lh2[c * 128 + 64 + f0A];
            const float4 lh0B = Lh2[c * 128 + f0B];
            const float4 lh1B = Lh2[c * 128 + 64 + f0B];
            #pragma unroll
            for (int r = 0; r < RPT; r++) {
                const float4 q = HR2v[(rb + r) * SV4 + c];
                pkf(ph[r][0], q.x, lo2(lh0A)); pkf(ph[r][0], q.y, hi2(lh0A));
                pkf(ph[r][0], q.z, lo2(lh1A)); pkf(ph[r][0], q.w, hi2(lh1A));
                pkf(ph[r][1], q.x, lo2(lh0B)); pkf(ph[r][1], q.y, hi2(lh0B));
                pkf(ph[r][1], q.z, lo2(lh1B)); pkf(ph[r][1], q.w, hi2(lh1B));
            }
        }
        #pragma unroll
        for (int r = 0; r < RPT; r++) {
            const int row = rb + r;
            const float mA0 = fmaf(z2[r][0].x, h2c[r][0].x, (1.0f - z2[r][0].x) * tanhf(ph[r][0].x));
            const float mA1 = fmaf(z2[r][0].y, h2c[r][0].y, (1.0f - z2[r][0].y) * tanhf(ph[r][0].y));
            const float mB0 = fmaf(z2[r][1].x, h2c[r][1].x, (1.0f - z2[r][1].x) * tanhf(ph[r][1].x));
            const float mB1 = fmaf(z2[r][1].y, h2c[r][1].y, (1.0f - z2[r][1].y) * tanhf(ph[r][1].y));
            sH2[row * S + f0A]      = mA0;
            sH2[row * S + f0A + 64] = mA1;
            sH2[row * S + f0B]      = mB0;
            sH2[row * S + f0B + 64] = mB1;
            if (row < NN) {
                oA0 += (double)mA0; oA1 += (double)mA1;
                oB0 += (double)mB0; oB1 += (double)mB1;
            }
        }
    };

    // ======== pipeline prologue: A computes step 0 ========
    if (isA) l1_p1(0);
    __syncthreads();
    if (isA) l1_p2(0);
    __syncthreads();

    // ======== main ticks: 2 barriers each ========
    for (int k = 0; k < TSTEPS; k++) {
        // alpha
        if (isA) {
            if (k + 1 < TSTEPS) l1_p1(k + 1);
        } else {
            if (k >= 1) l2_p5();     // finish step k-1
            l2_p3(k);
        }
        __syncthreads();  // b1: publishes sHR1(k+1), sAH(k), sH2(k-1)
        // beta
        if (isA) {
            if (k + 1 < TSTEPS) l1_p2(k + 1);
            if (t < NROW && k + 2 < TSTEPS) {   // sax prefetch for step k+2
                const float* xt = xb + (size_t)(k + 2) * NN;
                float a = 0.0f;
                for (int j = 0; j < NN; j++) a = fmaf(sA[t * NN + j], xt[j], a);
                sax[(k + 2) & 1][t] = a;
            }
        } else {
            l2_p4();
        }
        __syncthreads();  // b2: publishes H1(k+1), sHR2(k), sax(k+2)
    }

    // ---------- Epilogue: finish step T-1, mean over (T, nodes), cls ----------
    if (!isA) {
        l2_p5();  // step T-1 (sHR2 published at final b2)
        double vA0 = oA0, vA1 = oA1, vB0 = oB0, vB1 = oB1;
        #pragma unroll
        for (int off = 32; off >= 8; off >>= 1) {
            vA0 += __shfl_down(vA0, off, 64);
            vA1 += __shfl_down(vA1, off, 64);
            vB0 += __shfl_down(vB0, off, 64);
            vB1 += __shfl_down(vB1, off, 64);
        }
        if (rg == 0) {   // lane p of each B wave owns 4 columns
            sredD[f0A]      = vA0;
            sredD[f0A + 64] = vA1;
            sredD[f0B]      = vB0;
            sredD[f0B + 64] = vB1;
        }
    }
    __syncthreads();
    if (t < HID) {
        sredE[t] = (sredD[t] / (double)(TSTEPS * NN)) * (double)cls_w[t];
    }
    __syncthreads();
    if (t < 64) {
        double v = sredE[t] + sredE[t + 64];
        for (int off = 32; off; off >>= 1) v += __shfl_down(v, off, 64);
        if (t == 0) out[b] = (float)(v + (double)cls_b[0]);
    }
}

extern "C" void kernel_launch(void* const* d_in, const int* in_sizes, int n_in,
                              void* d_out, int out_size, void* d_ws, size_t ws_size,
                              hipStream_t stream) {
    const float* x    = (const float*)d_in[0];
    const int*   ei   = (const int*)  d_in[1];
    const float* ew   = (const float*)d_in[2];
    const float* Wz1  = (const float*)d_in[3];
    const float* bz1  = (const float*)d_in[4];
    const float* lzw1 = (const float*)d_in[5];
    const float* lzb1 = (const float*)d_in[6];
    const float* Wr1  = (const float*)d_in[7];
    const float* br1  = (const float*)d_in[8];
    const float* lrw1 = (const float*)d_in[9];
    const float* lrb1 = (const float*)d_in[10];
    const float* Wh1  = (const float*)d_in[11];
    const float* bh1  = (const float*)d_in[12];
    const float* lhw1 = (const float*)d_in[13];
    const float* lhb1 = (const float*)d_in[14];
    const float* Wz2  = (const float*)d_in[15];
    const float* bz2  = (const float*)d_in[16];
    const float* lzw2 = (const float*)d_in[17];
    const float* lzb2 = (const float*)d_in[18];
    const float* Wr2  = (const float*)d_in[19];
    const float* br2  = (const float*)d_in[20];
    const float* lrw2 = (const float*)d_in[21];
    const float* lrb2 = (const float*)d_in[22];
    const float* Wh2  = (const float*)d_in[23];
    const float* bh2  = (const float*)d_in[24];
    const float* lhw2 = (const float*)d_in[25];
    const float* lhb2 = (const float*)d_in[26];
    const float* clsw = (const float*)d_in[27];
    const float* clsb = (const float*)d_in[28];

    float* ws   = (float*)d_ws;
    float* outp = (float*)d_out;

    build_A<<<1, 64, 0, stream>>>(ei, ew, ws + WS_A);
    pack_bot<<<32, 256, 0, stream>>>(lzw1, lrw1, (float4*)(ws + WS_LZR1), 2);
    pack_bot<<<16, 256, 0, stream>>>(lhw1, lhw1, (float4*)(ws + WS_LH1), 1);
    pack_bot<<<32, 256, 0, stream>>>(lzw2, lrw2, (float4*)(ws + WS_LZR2), 2);
    pack_bot<<<16, 256, 0, stream>>>(lhw2, lhw2, (float4*)(ws + WS_LH2), 1);
    make_weff2<<<48, 256, 0, stream>>>(Wz2, Wr2, Wh2, lzw2, lrw2, lhw2,
                                       (float4*)(ws + WS_WE2));
    make_vecs<<<5, 256, 0, stream>>>(Wz1, Wr1, Wh1, bz1, br1, bh1,
                                     lzw1, lrw1, lhw1, lzb1, lrb1, lhb1,
                                     bz2, br2, bh2, lzw2, lrw2, lhw2,
                                     lzb2, lrb2, lhb2, ws + WS_VEC);
    tgcn_main<<<64, NTHREADS, 0, stream>>>(x, ws, clsw, clsb, outp);
}